// Round 13
// baseline (801.522 us; speedup 1.0000x reference)
//
#include <hip/hip_runtime.h>
#include <hip/hip_bf16.h>
#include <stdint.h>

#define E_EXP 8
#define NTOK  16384
#define DIN   1024
#define DEXP  2048
#define DOUT  1024
#define NSLOT (NTOK*2)
#define MAXT  136   // 32768/256 + 8 worst-case tiles (BM=256)

#define TS_T  (256*64)   // shorts per A/B K-tile (32KB), BK=64

typedef __attribute__((ext_vector_type(8))) short short8;
typedef __attribute__((ext_vector_type(8))) unsigned short ushort8;
typedef __attribute__((ext_vector_type(4))) unsigned short ushort4v;
typedef __attribute__((ext_vector_type(4))) float f32x4;

__device__ __forceinline__ unsigned short f2bf(float f){
  union { float f; uint32_t u; } v; v.f = f;
  uint32_t r = (v.u + 0x7FFFu + ((v.u >> 16) & 1u)) >> 16;  // RNE
  return (unsigned short)r;
}
__device__ __forceinline__ float bf2f(unsigned short u){
  union { uint32_t u; float f; } v; v.u = ((uint32_t)u) << 16;
  return v.f;
}

// async global->LDS, 16B per lane. LDS dest is wave-uniform base + lane*16.
__device__ __forceinline__ void async16(const void* g, void* l){
  __builtin_amdgcn_global_load_lds(
      (const __attribute__((address_space(1))) void*)g,
      (__attribute__((address_space(3))) void*)l, 16, 0, 0);
}

#define VMCNT8()  asm volatile("s_waitcnt vmcnt(8)"  ::: "memory")
#define VMCNT0()  asm volatile("s_waitcnt vmcnt(0)"  ::: "memory")
#define BARRIER() do { asm volatile("" ::: "memory"); __builtin_amdgcn_s_barrier(); asm volatile("" ::: "memory"); } while(0)

// ---------------- cast fp32 -> bf16, both weight tensors in one launch ----------------
__global__ __launch_bounds__(256) void cast2(const float* __restrict__ a,
                                             const float* __restrict__ b,
                                             unsigned short* __restrict__ da,
                                             unsigned short* __restrict__ db,
                                             int na, int nb){
  int i = (blockIdx.x*256 + threadIdx.x)*8;
  const float* s; unsigned short* d;
  if (i < na){ s = a + i; d = da + i; }
  else { int j = i - na; if (j >= nb) return; s = b + j; d = db + j; }
  float4 x = *(const float4*)(s);
  float4 y = *(const float4*)(s+4);
  ushort8 o;
  o[0]=f2bf(x.x); o[1]=f2bf(x.y); o[2]=f2bf(x.z); o[3]=f2bf(x.w);
  o[4]=f2bf(y.x); o[5]=f2bf(y.y); o[6]=f2bf(y.z); o[7]=f2bf(y.w);
  *(ushort8*)d = o;
}

// ---------------- router: logits, softmax, top-2, stats; fused x->bf16 ----------------
__global__ __launch_bounds__(256) void router(
    const float* __restrict__ x, const float* __restrict__ Wg, const float* __restrict__ bg,
    unsigned short* __restrict__ xb,
    int* __restrict__ eidx, float* __restrict__ gw,
    int* __restrict__ counts, float* __restrict__ probsum)
{
  __shared__ float sWg[E_EXP*DIN];
  __shared__ float sps[E_EXP];
  __shared__ int   scnt[E_EXP];
  const int tid = threadIdx.x;
  for (int i = tid; i < E_EXP*DIN; i += 256) sWg[i] = Wg[i];
  if (tid < E_EXP){ sps[tid]=0.f; scnt[tid]=0; }
  __syncthreads();
  const int lane = tid & 63;
  const int wv   = tid >> 6;
  for (int it = 0; it < 16; ++it){
    const int token = blockIdx.x*64 + wv*16 + it;
    float4 xv[4];
#pragma unroll
    for (int j=0;j<4;++j) xv[j] = *(const float4*)&x[(size_t)token*DIN + j*256 + lane*4];
#pragma unroll
    for (int j=0;j<4;++j){
      ushort4v o;
      o[0]=f2bf(xv[j].x); o[1]=f2bf(xv[j].y); o[2]=f2bf(xv[j].z); o[3]=f2bf(xv[j].w);
      *(ushort4v*)&xb[(size_t)token*DIN + j*256 + lane*4] = o;
    }
    float p[E_EXP];
#pragma unroll
    for (int e2=0;e2<E_EXP;++e2){
      float s = 0.f;
#pragma unroll
      for (int j=0;j<4;++j){
        const float4 w4 = *(const float4*)&sWg[e2*DIN + j*256 + lane*4];
        s += xv[j].x*w4.x + xv[j].y*w4.y + xv[j].z*w4.z + xv[j].w*w4.w;
      }
      p[e2] = s;
    }
#pragma unroll
    for (int d=1; d<64; d<<=1){
#pragma unroll
      for (int e2=0;e2<E_EXP;++e2) p[e2] += __shfl_xor(p[e2], d);
    }
    if (lane == 0){
      float mx = -1e30f;
#pragma unroll
      for (int e2=0;e2<E_EXP;++e2){ p[e2] += bg[e2]; mx = fmaxf(mx, p[e2]); }
      float se = 0.f;
#pragma unroll
      for (int e2=0;e2<E_EXP;++e2){ p[e2] = __expf(p[e2]-mx); se += p[e2]; }
      const float inv = 1.f/se;
#pragma unroll
      for (int e2=0;e2<E_EXP;++e2){ p[e2] *= inv; atomicAdd(&sps[e2], p[e2]); }
      int i1 = 0;
#pragma unroll
      for (int e2=1;e2<E_EXP;++e2) if (p[e2] > p[i1]) i1 = e2;   // strict > = lower-idx tiebreak
      int i2 = (i1==0) ? 1 : 0;
#pragma unroll
      for (int e2=0;e2<E_EXP;++e2) if (e2 != i1 && p[e2] > p[i2]) i2 = e2;
      const float v1 = p[i1], v2 = p[i2], s12 = v1 + v2;
      eidx[2*token]   = i1; eidx[2*token+1] = i2;
      gw[2*token]     = v1/s12; gw[2*token+1] = v2/s12;
      atomicAdd(&scnt[i1], 1); atomicAdd(&scnt[i2], 1);
    }
  }
  __syncthreads();
  if (tid < E_EXP){ atomicAdd(&counts[tid], scnt[tid]); atomicAdd(&probsum[tid], sps[tid]); }
}

// ---------------- finalize: loss, offsets, tile map (256-row tiles) ----------------
__global__ void finalize(const int* __restrict__ counts, const float* __restrict__ probsum,
                         float* __restrict__ loss_out, int* __restrict__ offs,
                         int* __restrict__ cursor, int* __restrict__ tile_e,
                         int* __restrict__ tile_row, int* __restrict__ ntiles)
{
  const int lane = threadIdx.x;   // 64 threads, 1 block
  int c[E_EXP];
#pragma unroll
  for (int e=0;e<E_EXP;++e) c[e] = counts[e];
  int off[E_EXP+1], tb[E_EXP+1];
  off[0]=0; tb[0]=0;
#pragma unroll
  for (int e=0;e<E_EXP;++e){ off[e+1]=off[e]+c[e]; tb[e+1]=tb[e]+((c[e]+255)>>8); }
  if (lane==0){
    float loss=0.f;
#pragma unroll
    for (int e=0;e<E_EXP;++e) loss += (float)c[e]*probsum[e];
    *loss_out = loss * (8.f/((float)NTOK*(float)NTOK));
    *ntiles = tb[E_EXP];
    offs[E_EXP] = off[E_EXP];
  }
  if (lane < E_EXP){ cursor[lane]=0; offs[lane]=off[lane]; }
  const int nt = tb[E_EXP];
  for (int i=lane; i<nt; i+=64){
    int e=0;
#pragma unroll
    for (int k=0;k<E_EXP-1;++k) if (i >= tb[k+1]) e = k+1;
    tile_e[i]   = e;
    tile_row[i] = off[e] + (i - tb[e])*256;
  }
}

// ---------------- scatter slots into expert buckets ----------------
__global__ __launch_bounds__(256) void scatter(const int* __restrict__ eidx,
    const float* __restrict__ gw,
    const int* __restrict__ offs, int* __restrict__ cursor,
    int* __restrict__ ptok, float* __restrict__ pw)
{
  const int t = blockIdx.x*256 + threadIdx.x;
  if (t >= NTOK) return;
#pragma unroll
  for (int s=0;s<2;++s){
    const int e2  = eidx[2*t+s];
    const int pos = offs[e2] + atomicAdd(&cursor[e2], 1);
    ptok[pos] = t;
    pw[pos]   = gw[2*t+s];
  }
}

// ============ grouped GEMM1: H = gather(x) @ W_in[e]^T + b_in[e] ============
// EXACT R9 structure (best measured): double-barrier + counted vmcnt(8),
// BM=256, BN=256, BK=64, XOR swizzle, XCD-chunked block swizzle.
__global__ __launch_bounds__(512) void gemm1(
    const unsigned short* __restrict__ xb,   // [NTOK,DIN] bf16
    const unsigned short* __restrict__ wib,  // [E,DEXP,DIN] bf16
    const float* __restrict__ b_in,          // [E,DEXP]
    unsigned short* __restrict__ H,          // [NSLOT,DEXP] bf16
    const int* __restrict__ ptok,
    const int* __restrict__ offs,
    const int* __restrict__ tile_e,
    const int* __restrict__ tile_row,
    const int* __restrict__ ntiles)
{
  const int gid   = (int)blockIdx.y * 8 + (int)blockIdx.x;
  const int rank  = (gid & 7) * 136 + (gid >> 3);
  const int rtile = rank >> 3;
  const int panel = rank & 7;
  if (rtile >= *ntiles) return;
  const int e    = tile_e[rtile];
  const int row0 = tile_row[rtile];
  const int seg_end = offs[e+1];
  const int col0 = panel * 256;

  __shared__ unsigned short As[2][TS_T];
  __shared__ unsigned short Bs[2][TS_T];

  const int tid  = threadIdx.x;
  const int lane = tid & 63;
  const int wv   = tid >> 6;
  const int wm   = wv >> 2;
  const int wn   = wv & 3;
  const int srow = tid >> 3;
  const int scol = ((tid & 7) ^ (srow & 7)) * 8;

  const unsigned short* ag[4];
#pragma unroll
  for (int i = 0; i < 4; ++i){
    int g = row0 + i*64 + srow; if (g > NSLOT-1) g = NSLOT-1;
    const int tok = ptok[g];
    ag[i] = xb + (size_t)tok*DIN + scol;
  }
  const unsigned short* bg4[4];
#pragma unroll
  for (int i = 0; i < 4; ++i)
    bg4[i] = wib + ((size_t)e*DEXP + col0 + i*64 + srow)*DIN + scol;
  float bias[4];
#pragma unroll
  for (int n = 0; n < 4; ++n)
    bias[n] = b_in[e*DEXP + col0 + wn*64 + n*16 + (lane&15)];

  f32x4 acc[8][4] = {};
  const int NK = DIN/64;   // 16
  int cur = 0;

  const unsigned int L0 = (wv*8)*64, L1 = (64+wv*8)*64, L2o = (128+wv*8)*64, L3 = (192+wv*8)*64;

  async16(ag[0],  &As[0][L0]);  async16(ag[1],  &As[0][L1]);
  async16(ag[2],  &As[0][L2o]); async16(ag[3],  &As[0][L3]);
  async16(bg4[0], &Bs[0][L0]);  async16(bg4[1], &Bs[0][L1]);
  async16(bg4[2], &Bs[0][L2o]); async16(bg4[3], &Bs[0][L3]);

  for (int kt = 0; kt < NK; ++kt){
    BARRIER();
    if (kt + 1 < NK){
      const int ko = (kt+1)*64;
      async16(ag[0]  + ko, &As[cur^1][L0]);  async16(ag[1]  + ko, &As[cur^1][L1]);
      async16(ag[2]  + ko, &As[cur^1][L2o]); async16(ag[3]  + ko, &As[cur^1][L3]);
      async16(bg4[0] + ko, &Bs[cur^1][L0]);  async16(bg4[1] + ko, &Bs[cur^1][L1]);
      async16(bg4[2] + ko, &Bs[cur^1][L2o]); async16(bg4[3] + ko, &Bs[cur^1][L3]);
      VMCNT8();
    } else {
      VMCNT0();
    }
    BARRIER();

    __builtin_amdgcn_s_setprio(1);
#pragma unroll
    for (int kk = 0; kk < 2; ++kk){
      const int ksl = ((kk*4 + (lane>>4)) ^ (lane & 7)) * 8;
      short8 a[8], b[4];
#pragma unroll
      for (int m = 0; m < 8; ++m)
        a[m] = *(const short8*)&As[cur][(wm*128 + m*16 + (lane&15))*64 + ksl];
#pragma unroll
      for (int n = 0; n < 4; ++n)
        b[n] = *(const short8*)&Bs[cur][(wn*64 + n*16 + (lane&15))*64 + ksl];
#pragma unroll
      for (int m = 0; m < 8; ++m)
#pragma unroll
        for (int n = 0; n < 4; ++n)
          acc[m][n] = __builtin_amdgcn_mfma_f32_16x16x32_bf16(a[m], b[n], acc[m][n], 0, 0, 0);
    }
    __builtin_amdgcn_s_setprio(0);
    cur ^= 1;
  }

#pragma unroll
  for (int m = 0; m < 8; ++m){
#pragma unroll
    for (int j = 0; j < 4; ++j){
      const int r = wm*128 + m*16 + (lane>>4)*4 + j;
      const int g = row0 + r;
      if (g < seg_end){
#pragma unroll
        for (int n = 0; n < 4; ++n){
          const int c = col0 + wn*64 + n*16 + (lane&15);
          H[(size_t)g*DEXP + c] = f2bf(acc[m][n][j] + bias[n]);
        }
      }
    }
  }
}

// ---------------- SoLU: act = softmax(h)*h per row, in place ----------------
__global__ __launch_bounds__(256) void solu(unsigned short* __restrict__ H){
  const size_t row = blockIdx.x;
  unsigned short* hp = H + row*DEXP;
  const int tid  = threadIdx.x;
  const int lane = tid & 63;
  const int wv   = tid >> 6;
  const short8 hv = *(const short8*)&hp[tid*8];
  float f[8];
#pragma unroll
  for (int j=0;j<8;++j) f[j] = bf2f((unsigned short)hv[j]);
  float mx = f[0];
#pragma unroll
  for (int j=1;j<8;++j) mx = fmaxf(mx, f[j]);
  for (int d=1; d<64; d<<=1) mx = fmaxf(mx, __shfl_xor(mx, d));
  __shared__ float redm[4];
  __shared__ float reds[4];
  if (lane==0) redm[wv] = mx;
  __syncthreads();
  mx = fmaxf(fmaxf(redm[0],redm[1]), fmaxf(redm[2],redm[3]));
  float se = 0.f; float ex[8];
#pragma unroll
  for (int j=0;j<8;++j){ ex[j] = __expf(f[j]-mx); se += ex[j]; }
  for (int d=1; d<64; d<<=1) se += __shfl_xor(se, d);
  if (lane==0) reds[wv] = se;
  __syncthreads();
  se = reds[0]+reds[1]+reds[2]+reds[3];
  const float inv = 1.0f/se;
  ushort8 o;
#pragma unroll
  for (int j=0;j<8;++j) o[j] = f2bf(f[j]*ex[j]*inv);
  *(ushort8*)&hp[tid*8] = o;
}

// ============ grouped GEMM2: out += w * (ACT @ W_out[e]^T), fused combine ============
// EXACT R9 K-loop (double-barrier + counted vmcnt(8)) + fused atomic combine
// epilogue (validated R10-R12: 2 addends/elem -> bitwise deterministic).
__global__ __launch_bounds__(512) void gemm2(
    const unsigned short* __restrict__ ACT,  // [NSLOT,DEXP] bf16
    const unsigned short* __restrict__ wob,  // [E,DOUT,DEXP] bf16
    float* __restrict__ out,                 // [NTOK,DOUT] fp32
    const int* __restrict__ ptok,
    const float* __restrict__ pw,
    const int* __restrict__ offs,
    const int* __restrict__ tile_e,
    const int* __restrict__ tile_row,
    const int* __restrict__ ntiles)
{
  const int gid   = (int)blockIdx.y * 4 + (int)blockIdx.x;
  const int rank  = (gid & 7) * 68 + (gid >> 3);
  const int rtile = rank >> 2;
  const int panel = rank & 3;
  if (rtile >= *ntiles) return;
  const int e    = tile_e[rtile];
  const int row0 = tile_row[rtile];
  const int seg_end = offs[e+1];
  const int col0 = panel * 256;

  __shared__ unsigned short As[2][TS_T];
  __shared__ unsigned short Bs[2][TS_T];

  const int tid  = threadIdx.x;
  const int lane = tid & 63;
  const int wv   = tid >> 6;
  const int wm   = wv >> 2;
  const int wn   = wv & 3;
  const int srow = tid >> 3;
  const int scol = ((tid & 7) ^ (srow & 7)) * 8;

  const unsigned short* ag[4];
#pragma unroll
  for (int i = 0; i < 4; ++i){
    int g = row0 + i*64 + srow; if (g > NSLOT-1) g = NSLOT-1;
    ag[i] = ACT + (size_t)g*DEXP + scol;
  }
  const unsigned short* bg4[4];
#pragma unroll
  for (int i = 0; i < 4; ++i)
    bg4[i] = wob + ((size_t)e*DOUT + col0 + i*64 + srow)*DEXP + scol;

  f32x4 acc[8][4] = {};
  const int NK = DEXP/64;  // 32
  int cur = 0;

  const unsigned int L0 = (wv*8)*64, L1 = (64+wv*8)*64, L2o = (128+wv*8)*64, L3 = (192+wv*8)*64;

  async16(ag[0],  &As[0][L0]);  async16(ag[1],  &As[0][L1]);
  async16(ag[2],  &As[0][L2o]); async16(ag[3],  &As[0][L3]);
  async16(bg4[0], &Bs[0][L0]);  async16(bg4[1], &Bs[0][L1]);
  async16(bg4[2], &Bs[0][L2o]); async16(bg4[3], &Bs[0][L3]);

  for (int kt = 0; kt < NK; ++kt){
    BARRIER();
    if (kt + 1 < NK){
      const int ko = (kt+1)*64;
      async16(ag[0]  + ko, &As[cur^1][L0]);  async16(ag[1]  + ko, &As[cur^1][L1]);
      async16(ag[2]  + ko, &As[cur^1][L2o]); async16(ag[3]  + ko, &As[cur^1][L3]);
      async16(bg4[0] + ko, &Bs[cur^1][L0]);  async16(bg4[1] + ko, &Bs[cur^1][L1]);
      async16(bg4[2] + ko, &Bs[cur^1][L2o]); async16(bg4[3] + ko, &Bs[cur^1][L3]);
      VMCNT8();
    } else {
      VMCNT0();
    }
    BARRIER();

    __builtin_amdgcn_s_setprio(1);
#pragma unroll
    for (int kk = 0; kk < 2; ++kk){
      const int ksl = ((kk*4 + (lane>>4)) ^ (lane & 7)) * 8;
      short8 a[8], b[4];
#pragma unroll
      for (int m = 0; m < 8; ++m)
        a[m] = *(const short8*)&As[cur][(wm*128 + m*16 + (lane&15))*64 + ksl];
#pragma unroll
      for (int n = 0; n < 4; ++n)
        b[n] = *(const short8*)&Bs[cur][(wn*64 + n*16 + (lane&15))*64 + ksl];
#pragma unroll
      for (int m = 0; m < 8; ++m)
#pragma unroll
        for (int n = 0; n < 4; ++n)
          acc[m][n] = __builtin_amdgcn_mfma_f32_16x16x32_bf16(a[m], b[n], acc[m][n], 0, 0, 0);
    }
    __builtin_amdgcn_s_setprio(0);
    cur ^= 1;
  }

  // fused combine: out[tok] += w * acc  (2 addends/elem -> bitwise deterministic)
#pragma unroll
  for (int m = 0; m < 8; ++m){
#pragma unroll
    for (int j = 0; j < 4; ++j){
      const int r = wm*128 + m*16 + (lane>>4)*4 + j;
      const int g = row0 + r;
      if (g < seg_end){
        const int tok   = ptok[g];
        const float wgt = pw[g];
        float* op = out + (size_t)tok*DOUT;
#pragma unroll
        for (int n = 0; n < 4; ++n){
          const int c = col0 + wn*64 + n*16 + (lane&15);
          unsafeAtomicAdd(op + c, wgt * acc[m][n][j]);
        }
      }
    }
  }
}

extern "C" void kernel_launch(void* const* d_in, const int* in_sizes, int n_in,
                              void* d_out, int out_size, void* d_ws, size_t ws_size,
                              hipStream_t stream)
{
  const float* x     = (const float*)d_in[0];
  const float* Wg    = (const float*)d_in[1];
  const float* bgp   = (const float*)d_in[2];
  const float* W_in  = (const float*)d_in[3];
  const float* b_in  = (const float*)d_in[4];
  const float* W_out = (const float*)d_in[5];
  float* out = (float*)d_out;

  char* base = (char*)d_ws;
  size_t o = 0;
  unsigned short* xb  = (unsigned short*)(base + o); o += (size_t)NTOK*DIN*2;
  unsigned short* wib = (unsigned short*)(base + o); o += (size_t)E_EXP*DEXP*DIN*2;
  unsigned short* wob = (unsigned short*)(base + o); o += (size_t)E_EXP*DOUT*DEXP*2;
  unsigned short* H   = (unsigned short*)(base + o); o += (size_t)NSLOT*DEXP*2;
  int*   eidx    = (int*)(base + o);   o += (size_t)NSLOT*4;
  float* gw      = (float*)(base + o); o += (size_t)NSLOT*4;
  int*   ptok    = (int*)(base + o);   o += (size_t)NSLOT*4;
  float* pw      = (float*)(base + o); o += (size_t)NSLOT*4;
  int*   counts  = (int*)(base + o);   o += 32;
  float* probsum = (float*)(base + o); o += 32;
  int*   cursor  = (int*)(base + o);   o += 32;
  int*   offs    = (int*)(base + o);   o += 64;
  int*   tile_e  = (int*)(base + o);   o += (size_t)MAXT*4;
  int*   tile_row= (int*)(base + o);   o += (size_t)MAXT*4;
  int*   ntiles  = (int*)(base + o);   o += 64;

  hipMemsetAsync(d_out, 0, (size_t)NTOK*DOUT*4 + 4, stream);   // out + loss slot
  hipMemsetAsync(counts, 0, 96, stream);

  cast2<<<dim3(16384), 256, 0, stream>>>(W_in, W_out, wib, wob,
                                         E_EXP*DEXP*DIN, E_EXP*DOUT*DEXP);

  router<<<dim3(256), 256, 0, stream>>>(x, Wg, bgp, xb, eidx, gw, counts, probsum);
  finalize<<<dim3(1), 64, 0, stream>>>(counts, probsum, out + (size_t)NTOK*DOUT,
                                       offs, cursor, tile_e, tile_row, ntiles);
  scatter<<<dim3(64), 256, 0, stream>>>(eidx, gw, offs, cursor, ptok, pw);

  gemm1<<<dim3(DEXP/256, MAXT), 512, 0, stream>>>(xb, wib, b_in, H, ptok, offs,
                                                  tile_e, tile_row, ntiles);
  solu<<<dim3(NSLOT), 256, 0, stream>>>(H);
  gemm2<<<dim3(DOUT/256, MAXT), 512, 0, stream>>>(H, wob, out, ptok, pw, offs,
                                                  tile_e, tile_row, ntiles);
}

// Round 14
// 738.670 us; speedup vs baseline: 1.0851x; 1.0851x over previous
//
#include <hip/hip_runtime.h>
#include <hip/hip_bf16.h>
#include <stdint.h>

#define E_EXP 8
#define NTOK  16384
#define DIN   1024
#define DEXP  2048
#define DOUT  1024
#define NSLOT (NTOK*2)
#define MAXT  136   // 32768/256 + 8 worst-case tiles (BM=256)

#define TS_T  (256*64)   // shorts per A/B K-tile (32KB)

typedef __attribute__((ext_vector_type(8))) short short8;
typedef __attribute__((ext_vector_type(8))) unsigned short ushort8;
typedef __attribute__((ext_vector_type(4))) unsigned short ushort4v;
typedef __attribute__((ext_vector_type(4))) float f32x4;

__device__ __forceinline__ unsigned short f2bf(float f){
  union { float f; uint32_t u; } v; v.f = f;
  uint32_t r = (v.u + 0x7FFFu + ((v.u >> 16) & 1u)) >> 16;  // RNE
  return (unsigned short)r;
}
__device__ __forceinline__ float bf2f(unsigned short u){
  union { uint32_t u; float f; } v; v.u = ((uint32_t)u) << 16;
  return v.f;
}

// async global->LDS, 16B per lane. LDS dest is wave-uniform base + lane*16.
__device__ __forceinline__ void async16(const void* g, void* l){
  __builtin_amdgcn_global_load_lds(
      (const __attribute__((address_space(1))) void*)g,
      (__attribute__((address_space(3))) void*)l, 16, 0, 0);
}

#define VMCNT8()  asm volatile("s_waitcnt vmcnt(8)"  ::: "memory")
#define VMCNT0()  asm volatile("s_waitcnt vmcnt(0)"  ::: "memory")
#define BARRIER() do { asm volatile("" ::: "memory"); __builtin_amdgcn_s_barrier(); asm volatile("" ::: "memory"); } while(0)

// ---------------- cast fp32 -> bf16, both weight tensors in one launch ----------------
__global__ __launch_bounds__(256) void cast2(const float* __restrict__ a,
                                             const float* __restrict__ b,
                                             unsigned short* __restrict__ da,
                                             unsigned short* __restrict__ db,
                                             int na, int nb){
  int i = (blockIdx.x*256 + threadIdx.x)*8;
  const float* s; unsigned short* d;
  if (i < na){ s = a + i; d = da + i; }
  else { int j = i - na; if (j >= nb) return; s = b + j; d = db + j; }
  float4 x = *(const float4*)(s);
  float4 y = *(const float4*)(s+4);
  ushort8 o;
  o[0]=f2bf(x.x); o[1]=f2bf(x.y); o[2]=f2bf(x.z); o[3]=f2bf(x.w);
  o[4]=f2bf(y.x); o[5]=f2bf(y.y); o[6]=f2bf(y.z); o[7]=f2bf(y.w);
  *(ushort8*)d = o;
}

// ---------------- router: logits, softmax, top-2, stats; fused x->bf16 ----------------
__global__ __launch_bounds__(256) void router(
    const float* __restrict__ x, const float* __restrict__ Wg, const float* __restrict__ bg,
    unsigned short* __restrict__ xb,
    int* __restrict__ eidx, float* __restrict__ gw,
    int* __restrict__ counts, float* __restrict__ probsum)
{
  __shared__ float sWg[E_EXP*DIN];
  __shared__ float sps[E_EXP];
  __shared__ int   scnt[E_EXP];
  const int tid = threadIdx.x;
  for (int i = tid; i < E_EXP*DIN; i += 256) sWg[i] = Wg[i];
  if (tid < E_EXP){ sps[tid]=0.f; scnt[tid]=0; }
  __syncthreads();
  const int lane = tid & 63;
  const int wv   = tid >> 6;
  for (int it = 0; it < 16; ++it){
    const int token = blockIdx.x*64 + wv*16 + it;
    float4 xv[4];
#pragma unroll
    for (int j=0;j<4;++j) xv[j] = *(const float4*)&x[(size_t)token*DIN + j*256 + lane*4];
#pragma unroll
    for (int j=0;j<4;++j){
      ushort4v o;
      o[0]=f2bf(xv[j].x); o[1]=f2bf(xv[j].y); o[2]=f2bf(xv[j].z); o[3]=f2bf(xv[j].w);
      *(ushort4v*)&xb[(size_t)token*DIN + j*256 + lane*4] = o;
    }
    float p[E_EXP];
#pragma unroll
    for (int e2=0;e2<E_EXP;++e2){
      float s = 0.f;
#pragma unroll
      for (int j=0;j<4;++j){
        const float4 w4 = *(const float4*)&sWg[e2*DIN + j*256 + lane*4];
        s += xv[j].x*w4.x + xv[j].y*w4.y + xv[j].z*w4.z + xv[j].w*w4.w;
      }
      p[e2] = s;
    }
#pragma unroll
    for (int d=1; d<64; d<<=1){
#pragma unroll
      for (int e2=0;e2<E_EXP;++e2) p[e2] += __shfl_xor(p[e2], d);
    }
    if (lane == 0){
      float mx = -1e30f;
#pragma unroll
      for (int e2=0;e2<E_EXP;++e2){ p[e2] += bg[e2]; mx = fmaxf(mx, p[e2]); }
      float se = 0.f;
#pragma unroll
      for (int e2=0;e2<E_EXP;++e2){ p[e2] = __expf(p[e2]-mx); se += p[e2]; }
      const float inv = 1.f/se;
#pragma unroll
      for (int e2=0;e2<E_EXP;++e2){ p[e2] *= inv; atomicAdd(&sps[e2], p[e2]); }
      int i1 = 0;
#pragma unroll
      for (int e2=1;e2<E_EXP;++e2) if (p[e2] > p[i1]) i1 = e2;   // strict > = lower-idx tiebreak
      int i2 = (i1==0) ? 1 : 0;
#pragma unroll
      for (int e2=0;e2<E_EXP;++e2) if (e2 != i1 && p[e2] > p[i2]) i2 = e2;
      const float v1 = p[i1], v2 = p[i2], s12 = v1 + v2;
      eidx[2*token]   = i1; eidx[2*token+1] = i2;
      gw[2*token]     = v1/s12; gw[2*token+1] = v2/s12;
      atomicAdd(&scnt[i1], 1); atomicAdd(&scnt[i2], 1);
    }
  }
  __syncthreads();
  if (tid < E_EXP){ atomicAdd(&counts[tid], scnt[tid]); atomicAdd(&probsum[tid], sps[tid]); }
}

// ---------------- finalize: loss, offsets, tile map (256-row tiles) ----------------
__global__ void finalize(const int* __restrict__ counts, const float* __restrict__ probsum,
                         float* __restrict__ loss_out, int* __restrict__ offs,
                         int* __restrict__ cursor, int* __restrict__ tile_e,
                         int* __restrict__ tile_row, int* __restrict__ ntiles)
{
  const int lane = threadIdx.x;   // 64 threads, 1 block
  int c[E_EXP];
#pragma unroll
  for (int e=0;e<E_EXP;++e) c[e] = counts[e];
  int off[E_EXP+1], tb[E_EXP+1];
  off[0]=0; tb[0]=0;
#pragma unroll
  for (int e=0;e<E_EXP;++e){ off[e+1]=off[e]+c[e]; tb[e+1]=tb[e]+((c[e]+255)>>8); }
  if (lane==0){
    float loss=0.f;
#pragma unroll
    for (int e=0;e<E_EXP;++e) loss += (float)c[e]*probsum[e];
    *loss_out = loss * (8.f/((float)NTOK*(float)NTOK));
    *ntiles = tb[E_EXP];
    offs[E_EXP] = off[E_EXP];
  }
  if (lane < E_EXP){ cursor[lane]=0; offs[lane]=off[lane]; }
  const int nt = tb[E_EXP];
  for (int i=lane; i<nt; i+=64){
    int e=0;
#pragma unroll
    for (int k=0;k<E_EXP-1;++k) if (i >= tb[k+1]) e = k+1;
    tile_e[i]   = e;
    tile_row[i] = off[e] + (i - tb[e])*256;
  }
}

// ---------------- scatter slots into expert buckets (+ inverse map) ----------------
__global__ __launch_bounds__(256) void scatter(const int* __restrict__ eidx,
    const int* __restrict__ offs, int* __restrict__ cursor,
    int* __restrict__ ptok, int* __restrict__ inv)
{
  const int t = blockIdx.x*256 + threadIdx.x;
  if (t >= NTOK) return;
#pragma unroll
  for (int s=0;s<2;++s){
    const int e2  = eidx[2*t+s];
    const int pos = offs[e2] + atomicAdd(&cursor[e2], 1);
    ptok[pos] = t;
    inv[2*t+s] = pos;
  }
}

// ============ grouped GEMM1: H = gather(x) @ W_in[e]^T + b_in[e] ============
// BM=256, BN=256, BK=64; 512 thr / 8 waves (2m x 4n), wave tile 128x64,
// acc[8][4]. Double-buffered LDS (128KB) + counted vmcnt(8) + XOR swizzle.
// R7-proven double-barrier skeleton + XCD-chunked block swizzle:
// each XCD owns a contiguous row-tile range across all col panels.
__global__ __launch_bounds__(512) void gemm1(
    const unsigned short* __restrict__ xb,   // [NTOK,DIN] bf16
    const unsigned short* __restrict__ wib,  // [E,DEXP,DIN] bf16
    const float* __restrict__ b_in,          // [E,DEXP]
    unsigned short* __restrict__ H,          // [NSLOT,DEXP] bf16
    const int* __restrict__ ptok,
    const int* __restrict__ offs,
    const int* __restrict__ tile_e,
    const int* __restrict__ tile_row,
    const int* __restrict__ ntiles)
{
  // bijective XCD-chunk swizzle: grid = 8 x 136 = 1088 blocks, 136 per XCD
  const int gid   = (int)blockIdx.y * 8 + (int)blockIdx.x;
  const int rank  = (gid & 7) * 136 + (gid >> 3);
  const int rtile = rank >> 3;        // 0..135
  const int panel = rank & 7;         // 0..7
  if (rtile >= *ntiles) return;
  const int e    = tile_e[rtile];
  const int row0 = tile_row[rtile];
  const int seg_end = offs[e+1];
  const int col0 = panel * 256;

  __shared__ unsigned short As[2][TS_T];
  __shared__ unsigned short Bs[2][TS_T];

  const int tid  = threadIdx.x;
  const int lane = tid & 63;
  const int wv   = tid >> 6;
  const int wm   = wv >> 2;            // 0..1  (128-row half)
  const int wn   = wv & 3;             // 0..3  (64-col panel)
  const int srow = tid >> 3;           // 0..63 staging row within issue
  const int scol = ((tid & 7) ^ (srow & 7)) * 8;   // swizzled source granule

  // ---- hoisted global reads ----
  const unsigned short* ag[4];
#pragma unroll
  for (int i = 0; i < 4; ++i){
    int g = row0 + i*64 + srow; if (g > NSLOT-1) g = NSLOT-1;
    const int tok = ptok[g];
    ag[i] = xb + (size_t)tok*DIN + scol;
  }
  const unsigned short* bg4[4];
#pragma unroll
  for (int i = 0; i < 4; ++i)
    bg4[i] = wib + ((size_t)e*DEXP + col0 + i*64 + srow)*DIN + scol;
  float bias[4];
#pragma unroll
  for (int n = 0; n < 4; ++n)
    bias[n] = b_in[e*DEXP + col0 + wn*64 + n*16 + (lane&15)];

  f32x4 acc[8][4] = {};
  const int NK = DIN/64;   // 16
  int cur = 0;

  const unsigned int L0 = (wv*8)*64, L1 = (64+wv*8)*64, L2o = (128+wv*8)*64, L3 = (192+wv*8)*64;

  // prologue: stage tile 0 into buf 0 (8 loads/thread)
  async16(ag[0],  &As[0][L0]);  async16(ag[1],  &As[0][L1]);
  async16(ag[2],  &As[0][L2o]); async16(ag[3],  &As[0][L3]);
  async16(bg4[0], &Bs[0][L0]);  async16(bg4[1], &Bs[0][L1]);
  async16(bg4[2], &Bs[0][L2o]); async16(bg4[3], &Bs[0][L3]);

  for (int kt = 0; kt < NK; ++kt){
    BARRIER();                          // all waves done reading buf[cur^1]
    if (kt + 1 < NK){
      const int ko = (kt+1)*64;
      async16(ag[0]  + ko, &As[cur^1][L0]);  async16(ag[1]  + ko, &As[cur^1][L1]);
      async16(ag[2]  + ko, &As[cur^1][L2o]); async16(ag[3]  + ko, &As[cur^1][L3]);
      async16(bg4[0] + ko, &Bs[cur^1][L0]);  async16(bg4[1] + ko, &Bs[cur^1][L1]);
      async16(bg4[2] + ko, &Bs[cur^1][L2o]); async16(bg4[3] + ko, &Bs[cur^1][L3]);
      VMCNT8();                         // tile kt's 8 loads have landed
    } else {
      VMCNT0();
    }
    BARRIER();                          // tile kt resident across all waves

    __builtin_amdgcn_s_setprio(1);
#pragma unroll
    for (int kk = 0; kk < 2; ++kk){
      const int ksl = ((kk*4 + (lane>>4)) ^ (lane & 7)) * 8;
      short8 a[8], b[4];
#pragma unroll
      for (int m = 0; m < 8; ++m)
        a[m] = *(const short8*)&As[cur][(wm*128 + m*16 + (lane&15))*64 + ksl];
#pragma unroll
      for (int n = 0; n < 4; ++n)
        b[n] = *(const short8*)&Bs[cur][(wn*64 + n*16 + (lane&15))*64 + ksl];
#pragma unroll
      for (int m = 0; m < 8; ++m)
#pragma unroll
        for (int n = 0; n < 4; ++n)
          acc[m][n] = __builtin_amdgcn_mfma_f32_16x16x32_bf16(a[m], b[n], acc[m][n], 0, 0, 0);
    }
    __builtin_amdgcn_s_setprio(0);
    cur ^= 1;
  }

#pragma unroll
  for (int m = 0; m < 8; ++m){
#pragma unroll
    for (int j = 0; j < 4; ++j){
      const int r = wm*128 + m*16 + (lane>>4)*4 + j;
      const int g = row0 + r;
      if (g < seg_end){
#pragma unroll
        for (int n = 0; n < 4; ++n){
          const int c = col0 + wn*64 + n*16 + (lane&15);
          H[(size_t)g*DEXP + c] = f2bf(acc[m][n][j] + bias[n]);
        }
      }
    }
  }
}

// ---------------- SoLU: act = softmax(h)*h per row, in place ----------------
__global__ __launch_bounds__(256) void solu(unsigned short* __restrict__ H){
  const size_t row = blockIdx.x;
  unsigned short* hp = H + row*DEXP;
  const int tid  = threadIdx.x;
  const int lane = tid & 63;
  const int wv   = tid >> 6;
  const short8 hv = *(const short8*)&hp[tid*8];
  float f[8];
#pragma unroll
  for (int j=0;j<8;++j) f[j] = bf2f((unsigned short)hv[j]);
  float mx = f[0];
#pragma unroll
  for (int j=1;j<8;++j) mx = fmaxf(mx, f[j]);
  for (int d=1; d<64; d<<=1) mx = fmaxf(mx, __shfl_xor(mx, d));
  __shared__ float redm[4];
  __shared__ float reds[4];
  if (lane==0) redm[wv] = mx;
  __syncthreads();
  mx = fmaxf(fmaxf(redm[0],redm[1]), fmaxf(redm[2],redm[3]));
  float se = 0.f; float ex[8];
#pragma unroll
  for (int j=0;j<8;++j){ ex[j] = __expf(f[j]-mx); se += ex[j]; }
  for (int d=1; d<64; d<<=1) se += __shfl_xor(se, d);
  if (lane==0) reds[wv] = se;
  __syncthreads();
  se = reds[0]+reds[1]+reds[2]+reds[3];
  const float inv = 1.0f/se;
  ushort8 o;
#pragma unroll
  for (int j=0;j<8;++j) o[j] = f2bf(f[j]*ex[j]*inv);
  *(ushort8*)&hp[tid*8] = o;
}

// ============ grouped GEMM2: Oslot = ACT @ W_out[e]^T (bf16, no atomics) ============
__global__ __launch_bounds__(512) void gemm2(
    const unsigned short* __restrict__ ACT,  // [NSLOT,DEXP] bf16
    const unsigned short* __restrict__ wob,  // [E,DOUT,DEXP] bf16
    unsigned short* __restrict__ Oslot,      // [NSLOT,DOUT] bf16
    const int* __restrict__ offs,
    const int* __restrict__ tile_e,
    const int* __restrict__ tile_row,
    const int* __restrict__ ntiles)
{
  // bijective XCD-chunk swizzle: grid = 4 x 136 = 544 blocks, 68 per XCD
  const int gid   = (int)blockIdx.y * 4 + (int)blockIdx.x;
  const int rank  = (gid & 7) * 68 + (gid >> 3);
  const int rtile = rank >> 2;        // 0..135
  const int panel = rank & 3;         // 0..3
  if (rtile >= *ntiles) return;
  const int e    = tile_e[rtile];
  const int row0 = tile_row[rtile];
  const int seg_end = offs[e+1];
  const int col0 = panel * 256;

  __shared__ unsigned short As[2][TS_T];
  __shared__ unsigned short Bs[2][TS_T];

  const int tid  = threadIdx.x;
  const int lane = tid & 63;
  const int wv   = tid >> 6;
  const int wm   = wv >> 2;
  const int wn   = wv & 3;
  const int srow = tid >> 3;
  const int scol = ((tid & 7) ^ (srow & 7)) * 8;

  const unsigned short* ag[4];
#pragma unroll
  for (int i = 0; i < 4; ++i){
    int g = row0 + i*64 + srow; if (g > NSLOT-1) g = NSLOT-1;
    ag[i] = ACT + (size_t)g*DEXP + scol;
  }
  const unsigned short* bg4[4];
#pragma unroll
  for (int i = 0; i < 4; ++i)
    bg4[i] = wob + ((size_t)e*DOUT + col0 + i*64 + srow)*DEXP + scol;

  f32x4 acc[8][4] = {};
  const int NK = DEXP/64;  // 32
  int cur = 0;

  const unsigned int L0 = (wv*8)*64, L1 = (64+wv*8)*64, L2o = (128+wv*8)*64, L3 = (192+wv*8)*64;

  async16(ag[0],  &As[0][L0]);  async16(ag[1],  &As[0][L1]);
  async16(ag[2],  &As[0][L2o]); async16(ag[3],  &As[0][L3]);
  async16(bg4[0], &Bs[0][L0]);  async16(bg4[1], &Bs[0][L1]);
  async16(bg4[2], &Bs[0][L2o]); async16(bg4[3], &Bs[0][L3]);

  for (int kt = 0; kt < NK; ++kt){
    BARRIER();
    if (kt + 1 < NK){
      const int ko = (kt+1)*64;
      async16(ag[0]  + ko, &As[cur^1][L0]);  async16(ag[1]  + ko, &As[cur^1][L1]);
      async16(ag[2]  + ko, &As[cur^1][L2o]); async16(ag[3]  + ko, &As[cur^1][L3]);
      async16(bg4[0] + ko, &Bs[cur^1][L0]);  async16(bg4[1] + ko, &Bs[cur^1][L1]);
      async16(bg4[2] + ko, &Bs[cur^1][L2o]); async16(bg4[3] + ko, &Bs[cur^1][L3]);
      VMCNT8();
    } else {
      VMCNT0();
    }
    BARRIER();

    __builtin_amdgcn_s_setprio(1);
#pragma unroll
    for (int kk = 0; kk < 2; ++kk){
      const int ksl = ((kk*4 + (lane>>4)) ^ (lane & 7)) * 8;
      short8 a[8], b[4];
#pragma unroll
      for (int m = 0; m < 8; ++m)
        a[m] = *(const short8*)&As[cur][(wm*128 + m*16 + (lane&15))*64 + ksl];
#pragma unroll
      for (int n = 0; n < 4; ++n)
        b[n] = *(const short8*)&Bs[cur][(wn*64 + n*16 + (lane&15))*64 + ksl];
#pragma unroll
      for (int m = 0; m < 8; ++m)
#pragma unroll
        for (int n = 0; n < 4; ++n)
          acc[m][n] = __builtin_amdgcn_mfma_f32_16x16x32_bf16(a[m], b[n], acc[m][n], 0, 0, 0);
    }
    __builtin_amdgcn_s_setprio(0);
    cur ^= 1;
  }

#pragma unroll
  for (int m = 0; m < 8; ++m){
#pragma unroll
    for (int j = 0; j < 4; ++j){
      const int r = wm*128 + m*16 + (lane>>4)*4 + j;
      const int g = row0 + r;
      if (g < seg_end){
#pragma unroll
        for (int n = 0; n < 4; ++n){
          const int c = col0 + wn*64 + n*16 + (lane&15);
          Oslot[(size_t)g*DOUT + c] = f2bf(acc[m][n][j]);
        }
      }
    }
  }
}

// ---------------- combine: out[t] = w0*Oslot[inv0] + w1*Oslot[inv1] ----------------
__global__ __launch_bounds__(256) void combine(const unsigned short* __restrict__ Oslot,
    const int* __restrict__ inv, const float* __restrict__ gw, float* __restrict__ out)
{
  const int t    = blockIdx.x*4 + (threadIdx.x >> 6);
  const int lane = threadIdx.x & 63;
  const int p0 = inv[2*t], p1 = inv[2*t+1];
  const float w0 = gw[2*t], w1 = gw[2*t+1];
  const unsigned short* r0 = Oslot + (size_t)p0*DOUT + lane*16;
  const unsigned short* r1 = Oslot + (size_t)p1*DOUT + lane*16;
  ushort8 a0 = *(const ushort8*)r0;
  ushort8 a1 = *(const ushort8*)(r0 + 8);
  ushort8 b0 = *(const ushort8*)r1;
  ushort8 b1 = *(const ushort8*)(r1 + 8);
  float* op = out + (size_t)t*DOUT + lane*16;
  float4 o;
#pragma unroll
  for (int q = 0; q < 2; ++q){
    const ushort8 ua = q ? a1 : a0;
    const ushort8 ub = q ? b1 : b0;
#pragma unroll
    for (int h = 0; h < 2; ++h){
      o.x = w0*bf2f(ua[h*4+0]) + w1*bf2f(ub[h*4+0]);
      o.y = w0*bf2f(ua[h*4+1]) + w1*bf2f(ub[h*4+1]);
      o.z = w0*bf2f(ua[h*4+2]) + w1*bf2f(ub[h*4+2]);
      o.w = w0*bf2f(ua[h*4+3]) + w1*bf2f(ub[h*4+3]);
      *(float4*)(op + q*8 + h*4) = o;
    }
  }
}

extern "C" void kernel_launch(void* const* d_in, const int* in_sizes, int n_in,
                              void* d_out, int out_size, void* d_ws, size_t ws_size,
                              hipStream_t stream)
{
  const float* x     = (const float*)d_in[0];
  const float* Wg    = (const float*)d_in[1];
  const float* bgp   = (const float*)d_in[2];
  const float* W_in  = (const float*)d_in[3];
  const float* b_in  = (const float*)d_in[4];
  const float* W_out = (const float*)d_in[5];
  float* out = (float*)d_out;

  char* base = (char*)d_ws;
  size_t o = 0;
  unsigned short* xb  = (unsigned short*)(base + o); o += (size_t)NTOK*DIN*2;       // 32 MB
  unsigned short* wib = (unsigned short*)(base + o); o += (size_t)E_EXP*DEXP*DIN*2; // 32 MB
  unsigned short* wob = (unsigned short*)(base + o); o += (size_t)E_EXP*DOUT*DEXP*2;
  unsigned short* H   = (unsigned short*)(base + o); o += (size_t)NSLOT*DEXP*2;
  // Oslot aliases xb+wib (both dead after gemm1) — 64 MB exactly
  unsigned short* Oslot = (unsigned short*)d_ws;
  int*   eidx    = (int*)(base + o);   o += (size_t)NSLOT*4;
  float* gw      = (float*)(base + o); o += (size_t)NSLOT*4;
  int*   ptok    = (int*)(base + o);   o += (size_t)NSLOT*4;
  int*   inv     = (int*)(base + o);   o += (size_t)NSLOT*4;
  int*   counts  = (int*)(base + o);   o += 32;
  float* probsum = (float*)(base + o); o += 32;
  int*   cursor  = (int*)(base + o);   o += 32;
  int*   offs    = (int*)(base + o);   o += 64;
  int*   tile_e  = (int*)(base + o);   o += (size_t)MAXT*4;
  int*   tile_row= (int*)(base + o);   o += (size_t)MAXT*4;
  int*   ntiles  = (int*)(base + o);   o += 64;

  hipMemsetAsync(counts, 0, 96, stream);  // counts+probsum+cursor (contiguous)

  cast2<<<dim3(16384), 256, 0, stream>>>(W_in, W_out, wib, wob,
                                         E_EXP*DEXP*DIN, E_EXP*DOUT*DEXP);

  router<<<dim3(256), 256, 0, stream>>>(x, Wg, bgp, xb, eidx, gw, counts, probsum);
  finalize<<<dim3(1), 64, 0, stream>>>(counts, probsum, out + (size_t)NTOK*DOUT,
                                       offs, cursor, tile_e, tile_row, ntiles);
  scatter<<<dim3(64), 256, 0, stream>>>(eidx, offs, cursor, ptok, inv);

  gemm1<<<dim3(DEXP/256, MAXT), 512, 0, stream>>>(xb, wib, b_in, H, ptok, offs,
                                                  tile_e, tile_row, ntiles);
  solu<<<dim3(NSLOT), 256, 0, stream>>>(H);
  gemm2<<<dim3(DOUT/256, MAXT), 512, 0, stream>>>(H, wob, Oslot, offs,
                                                  tile_e, tile_row, ntiles);
  combine<<<dim3(NTOK/4), 256, 0, stream>>>(Oslot, inv, gw, out);
}